// Round 5
// baseline (143.662 us; speedup 1.0000x reference)
//
#include <hip/hip_runtime.h>

// InverseBarkScale: 30-iter SGD with momentum inverting a bark filterbank.
// fb (513x128): freq f has taps only at columns (k1(f), k1(f)+1); k1 is
// monotone in f, so P(c) = {f : k1(f)=c} are contiguous and partition
// [0,513). |P(c)| <= ~3 for c<64, <= ~17 for c>=64.
//
// R5 (R4 was all-register already; this round cuts launch count + VALU):
//  - Lane l owns columns cA=l, cB=127-l and their primary freqs; spec/buf/
//    weights in registers (SA=6 + SB=20 zero-padded slots); cross-lane
//    traffic is 4 shfl-by-+-1 per iteration (snake pairing). No LDS.
//  - GC (=-2/N) folded into the diff values once per iter (4 muls) instead
//    of per-slot: -26 VALU/iter.
//  - setup: ONE single-block kernel. Taps per freq into LDS, then the
//    partition boundaries fstart[c] via the k1-crossing trick (thread f
//    writes fstart[c] for c in (k1(f-1), k1(f)] -- each c written exactly
//    once, no scan per column), then packed lane tables.
//  - scan: ONE single-block kernel (4 waves x float4 coalesced reduce of
//    bp[it][row], then thread0 runs the reference stop logic -> S).
// Stop semantics preserved: speculate 30 iters + loss log -> S; repair
// launch re-runs with S iters only if S<30 (expected: immediate exit).
// R4 lesson: ~90us of dur is harness d_ws-poison fill (41us, 268MB) +
// restore + graph overhead -- not controllable; minimize everything else.

#define NSTFT 513
#define NBARK 128
#define BATCH 4
#define TIME  512
#define MAXIT 30
#define NROWS (BATCH*TIME)      // 2048 rows, 1 wave each
#define SA 6                    // A-side slots (cols 0..63, max ~3 real)
#define SB 20                   // B-side slots (cols 64..127, max ~17 real)

// d_ws layout (bytes); ~260 KB. Every field written before read each call.
#define WS_S_OFF   0                          // int: stop iteration S
#define WS_HA_OFF  256                        // int2[64]: A {fbase,cnt}
#define WS_HB_OFF  768                        // int2[64]: B {fbase,cnt}
#define WS_WT_OFF  1280                       // float2[SA+SB][64]: {w1,w2}
#define WS_BP_OFF  14848                      // float[MAXIT][NROWS] partials

// ---- setup: taps + partition + lane tables, one block ----
__global__ __launch_bounds__(512) void setup_all(const float* __restrict__ fb,
                                                 char* __restrict__ ws) {
    __shared__ short  k1s[NSTFT];        // primary column per freq
    __shared__ float2 swt[NSTFT];        // {w1,w2} per freq
    __shared__ int    fstart[NBARK + 1]; // P(c) = [fstart[c], fstart[c+1])
    const int tid = threadIdx.x;

    // phase A: per-freq taps (first two nonzeros of row f; consecutive cols)
    for (int f = tid; f < NSTFT; f += 512) {
        const float* row = fb + (size_t)f * NBARK;
        int k1 = -1; float w1 = 0.f, w2 = 0.f;
        for (int k = 0; k < NBARK; ++k) {
            float w = row[k];
            if (w > 0.f) {
                if (k1 < 0) { k1 = k; w1 = w; }
                else        { w2 = w; break; }   // k2 == k1+1
            }
        }
        if (k1 < 0) k1 = (f < 256) ? 0 : 127;    // all-zero row: edge attach
        k1s[f] = (short)k1;
        swt[f] = make_float2(w1, w2);
    }
    __syncthreads();

    // phase B1: fstart via k1-crossings (k1 monotone, ends at 127)
    for (int f = tid; f < NSTFT; f += 512) {
        int kprev = (f == 0) ? -1 : (int)k1s[f - 1];
        int kcur  = (int)k1s[f];
        for (int c = kprev + 1; c <= kcur; ++c) fstart[c] = f;
    }
    if (tid == 0) fstart[NBARK] = NSTFT;
    __syncthreads();

    // phase B2: headers
    if (tid < NBARK) {
        const int c   = tid;
        const int cap = (c < 64) ? SA : SB;
        const int lf  = (c < 64) ? c  : 127 - c;
        int cnt = fstart[c + 1] - fstart[c];
        cnt = min(cnt, cap);                     // never fires if SA/SB sized
        ((int2*)(ws + (c < 64 ? WS_HA_OFF : WS_HB_OFF)))[lf] =
            make_int2(fstart[c], cnt);
    }
    // phase B3: packed weight tables (zero pads beyond cnt)
    float2* wt = (float2*)(ws + WS_WT_OFF);
    for (int t = tid; t < 64 * (SA + SB); t += 512) {
        const int slot = t >> 6, l = t & 63;
        const bool Aside = (slot < SA);
        const int c   = Aside ? l : 127 - l;
        const int i   = Aside ? slot : slot - SA;
        const int cap = Aside ? SA : SB;
        const int fs  = fstart[c];
        int cnt = min(fstart[c + 1] - fs, cap);
        wt[slot * 64 + l] = (i < cnt) ? swt[fs + i] : make_float2(0.f, 0.f);
    }
}

__global__ __launch_bounds__(64, 2) void
iter_kernel(const float* __restrict__ barkspec,
            const float* __restrict__ spec_init,
            float* __restrict__ out,
            char* __restrict__ ws, int mode)
{
    const int lane = threadIdx.x;            // single wave per block, no LDS

    int niter = MAXIT;
    if (mode) {
        int S = *(const volatile int*)(ws + WS_S_OFF);
        if (S >= MAXIT) return;              // expected path: no repair
        niter = S;
    }

    const int r     = blockIdx.x;
    const int batch = r >> 9;
    const int t     = r & (TIME - 1);

    // ---- per-lane tables -> registers ----
    const int2 hA = ((const int2*)(ws + WS_HA_OFF))[lane];
    const int2 hB = ((const int2*)(ws + WS_HB_OFF))[lane];
    const float2* wt = (const float2*)(ws + WS_WT_OFF);
    const float* spg = spec_init + ((size_t)batch*TIME + t)*NSTFT;

    float w1A[SA], w2A[SA], spA[SA], bfA[SA];
    float w1B[SB], w2B[SB], spB[SB], bfB[SB];
#pragma unroll
    for (int i = 0; i < SA; ++i) {
        float2 v = wt[i*64 + lane];
        w1A[i] = v.x; w2A[i] = v.y;
        spA[i] = (i < hA.y) ? spg[hA.x + i] : 0.f;
        bfA[i] = 0.f;
    }
#pragma unroll
    for (int i = 0; i < SB; ++i) {
        float2 v = wt[(SA + i)*64 + lane];
        w1B[i] = v.x; w2B[i] = v.y;
        spB[i] = (i < hB.y) ? spg[hB.x + i] : 0.f;
        bfB[i] = 0.f;
    }

    const float* bs = barkspec + (size_t)batch*NBARK*TIME + t;
    const float m0 = bs[(size_t)lane*TIME];          // col cA = lane
    const float m1 = bs[(size_t)(127 - lane)*TIME];  // col cB = 127-lane

    float* bp = (float*)(ws + WS_BP_OFF);
    const float GC = -2.0f / (float)NROWS;

    for (int it = 0; it < niter; ++it) {
        // ---- forward: per-column partial sums (unpredicated; pads are 0)
        float sAA = 0.f, sBA = 0.f, sAB = 0.f, sBB = 0.f;
#pragma unroll
        for (int i = 0; i < SA; ++i) {
            sAA = fmaf(spA[i], w1A[i], sAA);
            sBA = fmaf(spA[i], w2A[i], sBA);
        }
#pragma unroll
        for (int i = 0; i < SB; ++i) {
            sAB = fmaf(spB[i], w1B[i], sAB);
            sBB = fmaf(spB[i], w2B[i], sBB);
        }
        float cAin = __shfl_up(sBA, 1);   if (lane == 0)  cAin = 0.f;
        float cBin = __shfl_down(sBB, 1); if (lane == 63) cBin = sBA;
        const float d0 = m0 - (sAA + cAin);
        const float d1 = m1 - (sAB + cBin);

        if (!mode) {
            float lp = fmaf(d0, d0, d1*d1);
#pragma unroll
            for (int m = 32; m; m >>= 1) lp += __shfl_xor(lp, m);
            if (lane == 0) bp[it*NROWS + r] = lp;   // fire-and-forget
        }

        // ---- backward + SGD update; GC folded into diffs (4 muls, not 26)
        float dAn = __shfl_down(d0, 1); if (lane == 63) dAn = d1;
        float dBn = __shfl_up(d1, 1);   // lane0: its w2B are all 0
        const float g0 = GC * d0, gA = GC * dAn;
        const float g1 = GC * d1, gB = GC * dBn;
#pragma unroll
        for (int i = 0; i < SA; ++i) {
            float g = fmaf(g0, w1A[i], gA * w2A[i]);
            bfA[i] = fmaf(0.9f, bfA[i], g);
            float v = fmaf(-0.1f, bfA[i], spA[i]);
            spA[i] = v < 0.f ? 0.f : v;
        }
#pragma unroll
        for (int i = 0; i < SB; ++i) {
            float g = fmaf(g1, w1B[i], gB * w2B[i]);
            bfB[i] = fmaf(0.9f, bfB[i], g);
            float v = fmaf(-0.1f, bfB[i], spB[i]);
            spB[i] = v < 0.f ? 0.f : v;
        }
    }

    // ---- store out[batch, f, t] (scatter over f; each f stored once)
    float* og = out + ((size_t)batch*NSTFT)*TIME + t;
#pragma unroll
    for (int i = 0; i < SA; ++i)
        if (i < hA.y) og[(size_t)(hA.x + i)*TIME] = spA[i];
#pragma unroll
    for (int i = 0; i < SB; ++i)
        if (i < hB.y) og[(size_t)(hB.x + i)*TIME] = spB[i];
}

// ---- scan: reduce bp[it][.] (coalesced float4) + stop logic, one block ----
__global__ __launch_bounds__(256) void scan_all(char* __restrict__ ws) {
    __shared__ float losses[MAXIT];
    const int tid = threadIdx.x, wave = tid >> 6, lane = tid & 63;
    const float* bp = (const float*)(ws + WS_BP_OFF);
    for (int it = wave; it < MAXIT; it += 4) {
        const float4* b4 = (const float4*)(bp + (size_t)it*NROWS);
        float s = 0.f;
#pragma unroll
        for (int j = 0; j < NROWS/256; ++j) {      // 8 x float4 per lane
            float4 v = b4[j*64 + lane];
            s += (v.x + v.y) + (v.z + v.w);
        }
#pragma unroll
        for (int m = 32; m; m >>= 1) s += __shfl_xor(s, m);
        if (lane == 0) losses[it] = s * (1.0f/(float)NROWS);
    }
    __syncthreads();
    if (tid == 0) {
        // reference stop logic: update applied on the stop iteration,
        // frozen after -> S = first stop index + 1, else MAXIT
        float prev = __builtin_inff();
        int S = MAXIT;
        for (int i = 0; i < MAXIT; ++i) {
            float l = losses[i];
            if (l < 1e-5f || fabsf(prev - l) < 1e-8f) { S = i + 1; break; }
            prev = l;
        }
        *(int*)(ws + WS_S_OFF) = S;
    }
}

extern "C" void kernel_launch(void* const* d_in, const int* in_sizes, int n_in,
                              void* d_out, int out_size, void* d_ws, size_t ws_size,
                              hipStream_t stream)
{
    const float* barkspec  = (const float*)d_in[0];
    const float* fb        = (const float*)d_in[1];
    const float* spec_init = (const float*)d_in[2];
    float* out = (float*)d_out;
    char* ws = (char*)d_ws;

    setup_all  <<<1, 512, 0, stream>>>(fb, ws);
    iter_kernel<<<NROWS, 64, 0, stream>>>(barkspec, spec_init, out, ws, 0);
    scan_all   <<<1, 256, 0, stream>>>(ws);
    iter_kernel<<<NROWS, 64, 0, stream>>>(barkspec, spec_init, out, ws, 1);
}

// Round 6
// 129.033 us; speedup vs baseline: 1.1134x; 1.1134x over previous
//
#include <hip/hip_runtime.h>

// InverseBarkScale: 30-iter SGD with momentum inverting a bark filterbank.
// fb (513x128): freq f has taps only at columns (k1(f), k1(f)+1); k1 is
// monotone in f, so P(c) = {f : k1(f)=c} are contiguous and partition
// [0,513). |P(c)| <= ~3 for c<64, <= ~17 for c>=64.
//
// R6: R5's fused setup_all was 43us -- its phase A did a serial per-row scan
// with a value-dependent break = ~128 chained global loads on one CU.
// Fix: wave-ballot extraction (R4-style) inside the single setup block:
// wave handles f = wave + 8*step; lane loads float2 of row f (coalesced),
// two ballots -> k1; weights via shfl. Iterations independent -> pipelined.
// Everything else from R4/R5 kept:
//  - iter: all-register, lane owns cols (l, 127-l) + their primary freqs;
//    4 shfl-by-+-1 per iteration; GC folded into diffs; no LDS, no barriers.
//  - scan_all: 1024 threads, one iteration per wave, + inline stop logic.
// Stop semantics: speculate 30 iters + loss log -> S; repair launch re-runs
// with S iters only if S<30 (expected: immediate exit).
// Known floor: harness poison-fill of d_ws (268MB, ~41us @82% HBM) + input
// restore + graph gaps ~= 85-90us of dur; not controllable from here.

#define NSTFT 513
#define NBARK 128
#define BATCH 4
#define TIME  512
#define MAXIT 30
#define NROWS (BATCH*TIME)      // 2048 rows, 1 wave each
#define SA 6                    // A-side slots (cols 0..63, max ~3 real)
#define SB 20                   // B-side slots (cols 64..127, max ~17 real)

// d_ws layout (bytes); ~260 KB. Every field written before read each call.
#define WS_S_OFF   0                          // int: stop iteration S
#define WS_HA_OFF  256                        // int2[64]: A {fbase,cnt}
#define WS_HB_OFF  768                        // int2[64]: B {fbase,cnt}
#define WS_WT_OFF  1280                       // float2[SA+SB][64]: {w1,w2}
#define WS_BP_OFF  14848                      // float[MAXIT][NROWS] partials

// ---- setup: taps (wave-ballot) + partition + lane tables, one block ----
__global__ __launch_bounds__(512) void setup_all(const float* __restrict__ fb,
                                                 char* __restrict__ ws) {
    __shared__ short  k1s[NSTFT];        // primary column per freq
    __shared__ float2 swt[NSTFT];        // {w1,w2} per freq
    __shared__ int    fstart[NBARK + 1]; // P(c) = [fstart[c], fstart[c+1])
    const int tid = threadIdx.x, wave = tid >> 6, lane = tid & 63;

    // phase A: per-freq taps. Wave handles f = wave + 8*step; lane loads
    // float2 covering k = 2*lane, 2*lane+1 (one coalesced 512B load/row).
    // No loop-carried deps -> loads pipeline across steps.
#pragma unroll 4
    for (int f = wave; f < NSTFT; f += 8) {
        const float2 v = ((const float2*)(fb + (size_t)f * NBARK))[lane];
        unsigned long long mx = __ballot(v.x > 0.f);
        unsigned long long my = __ballot(v.y > 0.f);
        int kx = mx ? 2 * (__ffsll(mx) - 1)     : 999;
        int ky = my ? 2 * (__ffsll(my) - 1) + 1 : 999;
        int k1 = min(kx, ky);
        float w1 = 0.f, w2 = 0.f;
        if (k1 < NBARK) {
            float sx = __shfl(v.x, k1 >> 1);
            float sy = __shfl(v.y, k1 >> 1);
            w1 = (k1 & 1) ? sy : sx;
            const int k2 = k1 + 1;               // taps are consecutive cols
            if (k2 < NBARK) {
                float tx = __shfl(v.x, k2 >> 1);
                float ty = __shfl(v.y, k2 >> 1);
                w2 = (k2 & 1) ? ty : tx;         // ==0 if row has 1 tap
            }
        } else {
            k1 = (f < 256) ? 0 : 127;            // all-zero row: edge attach
        }
        if (lane == 0) { k1s[f] = (short)k1; swt[f] = make_float2(w1, w2); }
    }
    __syncthreads();

    // phase B1: fstart via k1-crossings (k1 monotone; each c written once)
    for (int f = tid; f < NSTFT; f += 512) {
        int kprev = (f == 0) ? -1 : (int)k1s[f - 1];
        int kcur  = (int)k1s[f];
        for (int c = kprev + 1; c <= kcur; ++c) fstart[c] = f;
    }
    if (tid == 0) fstart[NBARK] = NSTFT;
    __syncthreads();

    // phase B2: per-lane headers
    if (tid < NBARK) {
        const int c   = tid;
        const int cap = (c < 64) ? SA : SB;
        const int lf  = (c < 64) ? c  : 127 - c;
        int cnt = fstart[c + 1] - fstart[c];
        cnt = min(cnt, cap);
        ((int2*)(ws + (c < 64 ? WS_HA_OFF : WS_HB_OFF)))[lf] =
            make_int2(fstart[c], cnt);
    }
    // phase B3: packed weight tables (zero pads beyond cnt)
    float2* wt = (float2*)(ws + WS_WT_OFF);
    for (int t = tid; t < 64 * (SA + SB); t += 512) {
        const int slot = t >> 6, l = t & 63;
        const bool Aside = (slot < SA);
        const int c   = Aside ? l : 127 - l;
        const int i   = Aside ? slot : slot - SA;
        const int cap = Aside ? SA : SB;
        const int fs  = fstart[c];
        int cnt = min(fstart[c + 1] - fs, cap);
        wt[slot * 64 + l] = (i < cnt) ? swt[fs + i] : make_float2(0.f, 0.f);
    }
}

__global__ __launch_bounds__(64, 2) void
iter_kernel(const float* __restrict__ barkspec,
            const float* __restrict__ spec_init,
            float* __restrict__ out,
            char* __restrict__ ws, int mode)
{
    const int lane = threadIdx.x;            // single wave per block, no LDS

    int niter = MAXIT;
    if (mode) {
        int S = *(const volatile int*)(ws + WS_S_OFF);
        if (S >= MAXIT) return;              // expected path: no repair
        niter = S;
    }

    const int r     = blockIdx.x;
    const int batch = r >> 9;
    const int t     = r & (TIME - 1);

    // ---- per-lane tables -> registers ----
    const int2 hA = ((const int2*)(ws + WS_HA_OFF))[lane];
    const int2 hB = ((const int2*)(ws + WS_HB_OFF))[lane];
    const float2* wt = (const float2*)(ws + WS_WT_OFF);
    const float* spg = spec_init + ((size_t)batch*TIME + t)*NSTFT;

    float w1A[SA], w2A[SA], spA[SA], bfA[SA];
    float w1B[SB], w2B[SB], spB[SB], bfB[SB];
#pragma unroll
    for (int i = 0; i < SA; ++i) {
        float2 v = wt[i*64 + lane];
        w1A[i] = v.x; w2A[i] = v.y;
        spA[i] = (i < hA.y) ? spg[hA.x + i] : 0.f;
        bfA[i] = 0.f;
    }
#pragma unroll
    for (int i = 0; i < SB; ++i) {
        float2 v = wt[(SA + i)*64 + lane];
        w1B[i] = v.x; w2B[i] = v.y;
        spB[i] = (i < hB.y) ? spg[hB.x + i] : 0.f;
        bfB[i] = 0.f;
    }

    const float* bs = barkspec + (size_t)batch*NBARK*TIME + t;
    const float m0 = bs[(size_t)lane*TIME];          // col cA = lane
    const float m1 = bs[(size_t)(127 - lane)*TIME];  // col cB = 127-lane

    float* bp = (float*)(ws + WS_BP_OFF);
    const float GC = -2.0f / (float)NROWS;

    for (int it = 0; it < niter; ++it) {
        // ---- forward: per-column partial sums (unpredicated; pads are 0)
        float sAA = 0.f, sBA = 0.f, sAB = 0.f, sBB = 0.f;
#pragma unroll
        for (int i = 0; i < SA; ++i) {
            sAA = fmaf(spA[i], w1A[i], sAA);
            sBA = fmaf(spA[i], w2A[i], sBA);
        }
#pragma unroll
        for (int i = 0; i < SB; ++i) {
            sAB = fmaf(spB[i], w1B[i], sAB);
            sBB = fmaf(spB[i], w2B[i], sBB);
        }
        float cAin = __shfl_up(sBA, 1);   if (lane == 0)  cAin = 0.f;
        float cBin = __shfl_down(sBB, 1); if (lane == 63) cBin = sBA;
        const float d0 = m0 - (sAA + cAin);
        const float d1 = m1 - (sAB + cBin);

        if (!mode) {
            float lp = fmaf(d0, d0, d1*d1);
#pragma unroll
            for (int m = 32; m; m >>= 1) lp += __shfl_xor(lp, m);
            if (lane == 0) bp[it*NROWS + r] = lp;   // fire-and-forget
        }

        // ---- backward + SGD update; GC folded into diffs
        float dAn = __shfl_down(d0, 1); if (lane == 63) dAn = d1;
        float dBn = __shfl_up(d1, 1);   // lane0: its w2B are all 0
        const float g0 = GC * d0, gA = GC * dAn;
        const float g1 = GC * d1, gB = GC * dBn;
#pragma unroll
        for (int i = 0; i < SA; ++i) {
            float g = fmaf(g0, w1A[i], gA * w2A[i]);
            bfA[i] = fmaf(0.9f, bfA[i], g);
            float v = fmaf(-0.1f, bfA[i], spA[i]);
            spA[i] = v < 0.f ? 0.f : v;
        }
#pragma unroll
        for (int i = 0; i < SB; ++i) {
            float g = fmaf(g1, w1B[i], gB * w2B[i]);
            bfB[i] = fmaf(0.9f, bfB[i], g);
            float v = fmaf(-0.1f, bfB[i], spB[i]);
            spB[i] = v < 0.f ? 0.f : v;
        }
    }

    // ---- store out[batch, f, t] (scatter over f; each f stored once)
    float* og = out + ((size_t)batch*NSTFT)*TIME + t;
#pragma unroll
    for (int i = 0; i < SA; ++i)
        if (i < hA.y) og[(size_t)(hA.x + i)*TIME] = spA[i];
#pragma unroll
    for (int i = 0; i < SB; ++i)
        if (i < hB.y) og[(size_t)(hB.x + i)*TIME] = spB[i];
}

// ---- scan: 16 waves, one iteration each (coalesced float4) + stop logic ----
__global__ __launch_bounds__(1024) void scan_all(char* __restrict__ ws) {
    __shared__ float losses[MAXIT];
    const int tid = threadIdx.x, wave = tid >> 6, lane = tid & 63;
    const float* bp = (const float*)(ws + WS_BP_OFF);
    for (int it = wave; it < MAXIT; it += 16) {
        const float4* b4 = (const float4*)(bp + (size_t)it*NROWS);
        float s = 0.f;
#pragma unroll
        for (int j = 0; j < NROWS/256; ++j) {      // 8 x float4 per lane
            float4 v = b4[j*64 + lane];
            s += (v.x + v.y) + (v.z + v.w);
        }
#pragma unroll
        for (int m = 32; m; m >>= 1) s += __shfl_xor(s, m);
        if (lane == 0) losses[it] = s * (1.0f/(float)NROWS);
    }
    __syncthreads();
    if (tid == 0) {
        // reference stop logic: update applied on the stop iteration,
        // frozen after -> S = first stop index + 1, else MAXIT
        float prev = __builtin_inff();
        int S = MAXIT;
        for (int i = 0; i < MAXIT; ++i) {
            float l = losses[i];
            if (l < 1e-5f || fabsf(prev - l) < 1e-8f) { S = i + 1; break; }
            prev = l;
        }
        *(int*)(ws + WS_S_OFF) = S;
    }
}

extern "C" void kernel_launch(void* const* d_in, const int* in_sizes, int n_in,
                              void* d_out, int out_size, void* d_ws, size_t ws_size,
                              hipStream_t stream)
{
    const float* barkspec  = (const float*)d_in[0];
    const float* fb        = (const float*)d_in[1];
    const float* spec_init = (const float*)d_in[2];
    float* out = (float*)d_out;
    char* ws = (char*)d_ws;

    setup_all  <<<1, 512, 0, stream>>>(fb, ws);
    iter_kernel<<<NROWS, 64, 0, stream>>>(barkspec, spec_init, out, ws, 0);
    scan_all   <<<1, 1024, 0, stream>>>(ws);
    iter_kernel<<<NROWS, 64, 0, stream>>>(barkspec, spec_init, out, ws, 1);
}